// Round 12
// baseline (104.532 us; speedup 1.0000x reference)
//
#include <hip/hip_runtime.h>
#include <math.h>

#define NU 512
#define NCH 8192
#define CPB 32              // chains per block
#define NBLK 256            // 1 block/CU (96KB LDS)

typedef int i4 __attribute__((ext_vector_type(4)));
typedef float f2 __attribute__((ext_vector_type(2)));
typedef float f4 __attribute__((ext_vector_type(4)));

// R12 = R11 skeleton with K=4 load aging (loads for compute-phase q issued at
// q-4, ds_written at q-1, consumed at q): each batch ages TWO FULL PHASES
// before its vmcnt wait, so memory drain overlaps compute instead of
// serializing (R9-R11: drain+compute per phase = 13.7K cy ~= measured 15.5K).
// Depth lives in 4 rotating register sets (q0..q3); LDS layout, z path,
// compute wave, 18-barrier schedule: byte-identical to R11.
// vmcnt ramp (exact = #vmem ops issued after target batch, in-order queue):
//   p=0:16  p=1:16  p=2:20  p=3:24  p=4..12:28  p=13:20  p=14:12
__device__ __forceinline__ i4 mksrd(const void* p) {
    i4 v;
    v.x = (int)(unsigned)(uintptr_t)p;
    v.y = (int)((unsigned)((uintptr_t)p >> 32) & 0xFFFFu);
    v.z = (int)0xFFFFFFFFu;        // bounds check off
    v.w = 0x00020000;              // raw dword SRD
    return v;
}

__global__ __launch_bounds__(320, 1)
void reshopf_kernel(const float* __restrict__ Xr, const float* __restrict__ Xi,
                    const float* __restrict__ r0, const float* __restrict__ phi0,
                    const float* __restrict__ omegas,
                    float* __restrict__ zr, float* __restrict__ r_f,
                    float* __restrict__ phi_f)
{
    __shared__ float lds[24576];   // [R in: 0..32KB) [I in: 32..64KB) [z: 64..96KB)
    const int tid   = (int)threadIdx.x;
    const int lane  = tid & 63;
    const int wid   = __builtin_amdgcn_readfirstlane(tid >> 6);   // 0..4, uniform
    const int cbase = (int)blockIdx.x * CPB;
    const unsigned ldsb = (unsigned)(uintptr_t)&lds[0];

    if (wid < 4) {
        // ===================== LSU waves (dwordx4, 4-set ring) =====================
        const unsigned voff = ((unsigned)(lane >> 3)) * 32768u
                            + ((unsigned)(lane & 7)) * 16u;
        const i4 srdR = mksrd(Xr + cbase);
        const i4 srdI = mksrd(Xi + cbase);
        const i4 srdZ = mksrd(zr + cbase);
        const unsigned wl = ldsb + (unsigned)wid * 4096u
                          + ((unsigned)(lane >> 3)) * 128u
                          + ((unsigned)(lane & 7)) * 16u;

        f4 q0R[4], q0I[4], q1R[4], q1I[4];      // 4 rotating sets, static idx
        f4 q2R[4], q2I[4], q3R[4], q3I[4];
        f4 zv[4];

#define LD4(dst, srd, so) asm volatile("buffer_load_dwordx4 %0, %1, %2, %3 offen" \
        : "=v"(dst) : "v"(voff), "s"(srd), "s"(so))
#define LOADS(X, baseRow) { \
        const unsigned s0_ = ((unsigned)(baseRow) + (unsigned)wid * 32u) * 32768u; \
        LD4(X##R[0], srdR, s0_);            LD4(X##R[1], srdR, s0_ + 262144u); \
        LD4(X##R[2], srdR, s0_ + 524288u);  LD4(X##R[3], srdR, s0_ + 786432u); \
        LD4(X##I[0], srdI, s0_);            LD4(X##I[1], srdI, s0_ + 262144u); \
        LD4(X##I[2], srdI, s0_ + 524288u);  LD4(X##I[3], srdI, s0_ + 786432u); }

#define WRITES(X, HP) { const unsigned a_ = wl + (HP); \
        asm volatile("ds_write_b128 %0, %1 offset:0"     :: "v"(a_), "v"(X##R[0])); \
        asm volatile("ds_write_b128 %0, %1 offset:1024"  :: "v"(a_), "v"(X##R[1])); \
        asm volatile("ds_write_b128 %0, %1 offset:2048"  :: "v"(a_), "v"(X##R[2])); \
        asm volatile("ds_write_b128 %0, %1 offset:3072"  :: "v"(a_), "v"(X##R[3])); \
        asm volatile("ds_write_b128 %0, %1 offset:32768" :: "v"(a_), "v"(X##I[0])); \
        asm volatile("ds_write_b128 %0, %1 offset:33792" :: "v"(a_), "v"(X##I[1])); \
        asm volatile("ds_write_b128 %0, %1 offset:34816" :: "v"(a_), "v"(X##I[2])); \
        asm volatile("ds_write_b128 %0, %1 offset:35840" :: "v"(a_), "v"(X##I[3])); }

#define ZREADS(HP) { const unsigned a_ = wl + 65536u + (HP); \
        asm volatile("ds_read_b128 %0, %1 offset:0"    : "=v"(zv[0]) : "v"(a_)); \
        asm volatile("ds_read_b128 %0, %1 offset:1024" : "=v"(zv[1]) : "v"(a_)); \
        asm volatile("ds_read_b128 %0, %1 offset:2048" : "=v"(zv[2]) : "v"(a_)); \
        asm volatile("ds_read_b128 %0, %1 offset:3072" : "=v"(zv[3]) : "v"(a_)); }

#define ZSTORES(baseRow) { \
        const unsigned s0_ = ((unsigned)(baseRow) + (unsigned)wid * 32u) * 32768u; \
        asm volatile("buffer_store_dwordx4 %0, %1, %2, %3 offen" \
            :: "v"(zv[0]), "v"(voff), "s"(srdZ), "s"(s0_) : "memory"); \
        asm volatile("buffer_store_dwordx4 %0, %1, %2, %3 offen" \
            :: "v"(zv[1]), "v"(voff), "s"(srdZ), "s"(s0_ + 262144u) : "memory"); \
        asm volatile("buffer_store_dwordx4 %0, %1, %2, %3 offen" \
            :: "v"(zv[2]), "v"(voff), "s"(srdZ), "s"(s0_ + 524288u) : "memory"); \
        asm volatile("buffer_store_dwordx4 %0, %1, %2, %3 offen" \
            :: "v"(zv[3]), "v"(voff), "s"(srdZ), "s"(s0_ + 786432u) : "memory"); }

#define WAITVM(N) asm volatile("s_waitcnt vmcnt(%0)" :: "n"(N) : "memory")
#define WAITLG    asm volatile("s_waitcnt lgkmcnt(0)" ::: "memory")
#define WAITEX    asm volatile("s_waitcnt expcnt(0)" ::: "memory")

        // ---- phase body: W = write set (data for phase p+1), L = load set
        //      (data for phase p+4), Z = store z(p-1). HP(p+1) = ((p+1)&1)*16K.
#define PHASE_W(SETW, NW, P)  { WAITVM(NW); WRITES(SETW, (((P)+1)&1)*16384u); }
#define PHASE_L(SETL, P)      { LOADS(SETL, ((P)+4)*128); }
#define PHASE_Z(P)            { WAITEX; ZREADS((((P)-1)&1)*16384u); WAITLG; \
                                ZSTORES(((P)-1)*128); }
#define PHASE_END             { WAITLG; __builtin_amdgcn_s_barrier(); }

        // prologue: pre-issue 4 batches (compute phases 0..3)
        LOADS(q0, 0); LOADS(q1, 128); LOADS(q2, 256); LOADS(q3, 384);
        __builtin_amdgcn_s_barrier();                              // #1
        WAITVM(24);                 // loads(0) done (24 = q1,q2,q3 after it)
        WRITES(q0, 0u);             // slot 0 = compute phase 0
        WAITLG;
        __builtin_amdgcn_s_barrier();                              // #2

        // p=0..3 (ramp)
        PHASE_W(q1, 16, 0) PHASE_L(q0, 0)            PHASE_END     // #3
        PHASE_W(q2, 16, 1) PHASE_L(q1, 1) PHASE_Z(1) PHASE_END     // #4
        PHASE_W(q3, 20, 2) PHASE_L(q2, 2) PHASE_Z(2) PHASE_END     // #5
        PHASE_W(q0, 24, 3) PHASE_L(q3, 3) PHASE_Z(3) PHASE_END     // #6
        // p=4..11 (steady, 2 blocks of 4)
        for (int b = 0; b < 2; ++b) {
            const int p0 = 4 + b * 4;
            PHASE_W(q1, 28, p0 + 0) PHASE_L(q0, p0 + 0) PHASE_Z(p0 + 0) PHASE_END
            PHASE_W(q2, 28, p0 + 1) PHASE_L(q1, p0 + 1) PHASE_Z(p0 + 1) PHASE_END
            PHASE_W(q3, 28, p0 + 2) PHASE_L(q2, p0 + 2) PHASE_Z(p0 + 2) PHASE_END
            PHASE_W(q0, 28, p0 + 3) PHASE_L(q3, p0 + 3) PHASE_Z(p0 + 3) PHASE_END
        }                                                          // #7..#14
        // p=12..14 (tail: no more loads)
        PHASE_W(q1, 28, 12) PHASE_Z(12) PHASE_END                  // #15
        PHASE_W(q2, 20, 13) PHASE_Z(13) PHASE_END                  // #16
        PHASE_W(q3, 12, 14) PHASE_Z(14) PHASE_END                  // #17
        // p=15: consume only
        PHASE_Z(15) PHASE_END                                      // #18
        // post: store z(15) (slot 15&1 = 1)
        WAITEX; ZREADS(16384u); WAITLG; ZSTORES(15 * 128);
    } else {
        // ===================== compute wave (verbatim R9/R10/R11) =====================
        const int l   = lane & 31;            // lanes 32-63 duplicate 0-31
        const int gch = cbase + l;
        const float INV2PI = 0.15915494309189533577f;

        const float wo    = omegas[gch & (NU - 1)];
        const float sig   = 1.0f / (1.0f + __expf(-wo));
        const float a_rev = (sig * 19.5f + 0.5f) * 0.01f;
        const float Ca    = __builtin_amdgcn_cosf(a_rev);
        const float Sa    = __builtin_amdgcn_sinf(a_rev);

        float r        = r0[gch];
        const float p0 = phi0[gch];
        float s = __builtin_amdgcn_sinf(p0 * INV2PI);
        float c = __builtin_amdgcn_cosf(p0 * INV2PI);
        float acc = 0.0f;

        const unsigned vR = ldsb + (unsigned)l * 4u;
        const unsigned vI = vR + 32768u;
        const unsigned vZ = vR + 65536u;

        auto step = [&](float xr, float xi, float& zout) {
            const float kxi = xi * -0.05f;
            const float kxr = xr * 0.05f;
            const float eps = kxi * s;
            const float t1  = s * Ca;
            const float sA  = fmaf(c, Sa, t1);
            const float t2  = c * Ca;
            const float cA  = fmaf(-s, Sa, t2);
            const float rr  = r * r;
            const float g1  = fmaf(-rr, r, r);
            const float tr  = fmaf(kxr, c, r);
            r = fmaf(0.01f, g1, tr);
            s = fmaf(eps, cA, sA);
            c = fmaf(-eps, sA, cA);
            acc += eps;
            zout = r * c;
        };

#define RD(it, R01, R23, I01, I23) { \
        const unsigned so_ = ((unsigned)((it) & 63)) * 512u; \
        const unsigned aR_ = vR + so_, aI_ = vI + so_; \
        asm volatile("ds_read2_b32 %0, %1 offset0:0 offset1:32"  : "=v"(R01) : "v"(aR_)); \
        asm volatile("ds_read2_b32 %0, %1 offset0:64 offset1:96" : "=v"(R23) : "v"(aR_)); \
        asm volatile("ds_read2_b32 %0, %1 offset0:0 offset1:32"  : "=v"(I01) : "v"(aI_)); \
        asm volatile("ds_read2_b32 %0, %1 offset0:64 offset1:96" : "=v"(I23) : "v"(aI_)); }

#define COMP(it, R01, R23, I01, I23) { \
        float z0_, z1_, z2_, z3_; \
        step(R01.x, I01.x, z0_); step(R01.y, I01.y, z1_); \
        step(R23.x, I23.x, z2_); step(R23.y, I23.y, z3_); \
        const float m_ = fmaf(s, s, c * c); \
        const float n_ = fmaf(-0.5f, m_, 1.5f); \
        s *= n_; c *= n_; \
        const unsigned aZ_ = vZ + ((unsigned)((it) & 63)) * 512u; \
        asm volatile("ds_write2_b32 %0, %1, %2 offset0:0 offset1:32"  :: "v"(aZ_), "v"(z0_), "v"(z1_)); \
        asm volatile("ds_write2_b32 %0, %1, %2 offset0:64 offset1:96" :: "v"(aZ_), "v"(z2_), "v"(z3_)); }

#define W4 { asm volatile("s_waitcnt lgkmcnt(4)" ::: "memory"); __builtin_amdgcn_sched_barrier(0); }
#define W0 { asm volatile("s_waitcnt lgkmcnt(0)" ::: "memory"); __builtin_amdgcn_sched_barrier(0); }

        __builtin_amdgcn_s_barrier();                              // #1
        __builtin_amdgcn_s_barrier();                              // #2  (slot0 sealed)

        f2 Ar01, Ar23, Ai01, Ai23, Br01, Br23, Bi01, Bi23;
        for (int p = 0; p < 16; ++p) {
            const int it0 = p * 32;
            RD(it0, Ar01, Ar23, Ai01, Ai23);
            for (int j = 0; j < 15; ++j) {
                const int k = it0 + 2 * j;
                RD(k + 1, Br01, Br23, Bi01, Bi23); W4; COMP(k,     Ar01, Ar23, Ai01, Ai23);
                RD(k + 2, Ar01, Ar23, Ai01, Ai23); W4; COMP(k + 1, Br01, Br23, Bi01, Bi23);
            }
            RD(it0 + 31, Br01, Br23, Bi01, Bi23); W4; COMP(it0 + 30, Ar01, Ar23, Ai01, Ai23);
            W0; COMP(it0 + 31, Br01, Br23, Bi01, Bi23);
            asm volatile("s_waitcnt lgkmcnt(0)" ::: "memory");     // z writes sealed
            __builtin_amdgcn_s_barrier();                          // #3..#18
        }

        if (lane < 32) {
            r_f[gch] = r;
            phi_f[gch] = (float)((double)p0
                         + (double)a_rev * 2048.0 * 6.283185307179586476925287
                         + (double)acc);
        }
    }
}

extern "C" void kernel_launch(void* const* d_in, const int* in_sizes, int n_in,
                              void* d_out, int out_size, void* d_ws, size_t ws_size,
                              hipStream_t stream) {
    const float* Xr   = (const float*)d_in[0];
    const float* Xi   = (const float*)d_in[1];
    const float* r0   = (const float*)d_in[2];
    const float* phi0 = (const float*)d_in[3];
    const float* om   = (const float*)d_in[4];

    float* out   = (float*)d_out;
    float* zrp   = out;                               // Re(z): T*NCH floats
    float* r_f   = out + (size_t)2048 * NCH;          // NCH floats
    float* phi_f = r_f + NCH;                         // NCH floats

    reshopf_kernel<<<NBLK, 320, 0, stream>>>(Xr, Xi, r0, phi0, om, zrp, r_f, phi_f);
}

// Round 13
// 98.620 us; speedup vs baseline: 1.0600x; 1.0600x over previous
//
#include <hip/hip_runtime.h>
#include <math.h>

#define NU 512
#define NCH 8192
#define CPB 32              // chains per block
#define NBLK 256            // 1 block/CU (96KB LDS)

typedef int i4 __attribute__((ext_vector_type(4)));
typedef float f2 __attribute__((ext_vector_type(2)));
typedef float f4 __attribute__((ext_vector_type(4)));

// R13 = R11 skeleton; ONLY the compute wave changed: 4 rotating register
// sets, ds_reads issued 2 iterations ahead, counted lgkm waits (12 steady;
// ramp 8/10 at phase head, 8/4 at tail) so no DS wait targets an op younger
// than ~2 iterations (~340cy >> 120cy DS latency). Look-ahead clamped at the
// half boundary (max RD slot = s0+31) -> no race with LSU's same-phase
// writes of the next half. LSU waves + barriers verbatim R11.
__device__ __forceinline__ i4 mksrd(const void* p) {
    i4 v;
    v.x = (int)(unsigned)(uintptr_t)p;
    v.y = (int)((unsigned)((uintptr_t)p >> 32) & 0xFFFFu);
    v.z = (int)0xFFFFFFFFu;        // bounds check off
    v.w = 0x00020000;              // raw dword SRD
    return v;
}

__global__ __launch_bounds__(320, 1)
void reshopf_kernel(const float* __restrict__ Xr, const float* __restrict__ Xi,
                    const float* __restrict__ r0, const float* __restrict__ phi0,
                    const float* __restrict__ omegas,
                    float* __restrict__ zr, float* __restrict__ r_f,
                    float* __restrict__ phi_f)
{
    __shared__ float lds[24576];   // [R in: 0..32KB) [I in: 32..64KB) [z: 64..96KB)
    const int tid   = (int)threadIdx.x;
    const int lane  = tid & 63;
    const int wid   = __builtin_amdgcn_readfirstlane(tid >> 6);   // 0..4, uniform
    const int cbase = (int)blockIdx.x * CPB;
    const unsigned ldsb = (unsigned)(uintptr_t)&lds[0];

    if (wid < 4) {
        // ===================== LSU waves (verbatim R11) =====================
        const unsigned voff = ((unsigned)(lane >> 3)) * 32768u
                            + ((unsigned)(lane & 7)) * 16u;
        const i4 srdR = mksrd(Xr + cbase);
        const i4 srdI = mksrd(Xi + cbase);
        const i4 srdZ = mksrd(zr + cbase);
        const unsigned wl = ldsb + (unsigned)wid * 4096u
                          + ((unsigned)(lane >> 3)) * 128u
                          + ((unsigned)(lane & 7)) * 16u;

        f4 aR[4], aI[4], bR[4], bI[4], zv[4];   // static-indexed only

#define LD4(dst, srd, so) asm volatile("buffer_load_dwordx4 %0, %1, %2, %3 offen" \
        : "=v"(dst) : "v"(voff), "s"(srd), "s"(so))
#define LOADS(X, baseRow) { \
        const unsigned s0_ = ((unsigned)(baseRow) + (unsigned)wid * 32u) * 32768u; \
        LD4(X##R[0], srdR, s0_);            LD4(X##R[1], srdR, s0_ + 262144u); \
        LD4(X##R[2], srdR, s0_ + 524288u);  LD4(X##R[3], srdR, s0_ + 786432u); \
        LD4(X##I[0], srdI, s0_);            LD4(X##I[1], srdI, s0_ + 262144u); \
        LD4(X##I[2], srdI, s0_ + 524288u);  LD4(X##I[3], srdI, s0_ + 786432u); }

#define WRITES(X, HP) { const unsigned a_ = wl + (HP); \
        asm volatile("ds_write_b128 %0, %1 offset:0"     :: "v"(a_), "v"(X##R[0])); \
        asm volatile("ds_write_b128 %0, %1 offset:1024"  :: "v"(a_), "v"(X##R[1])); \
        asm volatile("ds_write_b128 %0, %1 offset:2048"  :: "v"(a_), "v"(X##R[2])); \
        asm volatile("ds_write_b128 %0, %1 offset:3072"  :: "v"(a_), "v"(X##R[3])); \
        asm volatile("ds_write_b128 %0, %1 offset:32768" :: "v"(a_), "v"(X##I[0])); \
        asm volatile("ds_write_b128 %0, %1 offset:33792" :: "v"(a_), "v"(X##I[1])); \
        asm volatile("ds_write_b128 %0, %1 offset:34816" :: "v"(a_), "v"(X##I[2])); \
        asm volatile("ds_write_b128 %0, %1 offset:35840" :: "v"(a_), "v"(X##I[3])); }

#define ZREADS(HP) { const unsigned a_ = wl + 65536u + (HP); \
        asm volatile("ds_read_b128 %0, %1 offset:0"    : "=v"(zv[0]) : "v"(a_)); \
        asm volatile("ds_read_b128 %0, %1 offset:1024" : "=v"(zv[1]) : "v"(a_)); \
        asm volatile("ds_read_b128 %0, %1 offset:2048" : "=v"(zv[2]) : "v"(a_)); \
        asm volatile("ds_read_b128 %0, %1 offset:3072" : "=v"(zv[3]) : "v"(a_)); }

#define ZSTORES(baseRow) { \
        const unsigned s0_ = ((unsigned)(baseRow) + (unsigned)wid * 32u) * 32768u; \
        asm volatile("buffer_store_dwordx4 %0, %1, %2, %3 offen" \
            :: "v"(zv[0]), "v"(voff), "s"(srdZ), "s"(s0_) : "memory"); \
        asm volatile("buffer_store_dwordx4 %0, %1, %2, %3 offen" \
            :: "v"(zv[1]), "v"(voff), "s"(srdZ), "s"(s0_ + 262144u) : "memory"); \
        asm volatile("buffer_store_dwordx4 %0, %1, %2, %3 offen" \
            :: "v"(zv[2]), "v"(voff), "s"(srdZ), "s"(s0_ + 524288u) : "memory"); \
        asm volatile("buffer_store_dwordx4 %0, %1, %2, %3 offen" \
            :: "v"(zv[3]), "v"(voff), "s"(srdZ), "s"(s0_ + 786432u) : "memory"); }

#define WAITVM(N) asm volatile("s_waitcnt vmcnt(%0)" :: "n"(N) : "memory")
#define WAITLG    asm volatile("s_waitcnt lgkmcnt(0)" ::: "memory")
#define WAITEX    asm volatile("s_waitcnt expcnt(0)" ::: "memory")

        // P(-2): pre-issue BOTH halves
        LOADS(a, 0);
        LOADS(b, 128);
        __builtin_amdgcn_s_barrier();                              // #1
        WAITVM(8);
        WRITES(a, 0u);
        WAITLG;
        __builtin_amdgcn_s_barrier();                              // #2

        // phase 0
        WAITVM(0);
        WRITES(b, 16384u);
        LOADS(a, 256);
        WAITLG;
        __builtin_amdgcn_s_barrier();                              // #3
        // phase 1
        WAITVM(0);
        WRITES(a, 0u);
        LOADS(b, 384);
        WAITEX;
        ZREADS(0u);
        WAITLG;
        ZSTORES(0);
        __builtin_amdgcn_s_barrier();                              // #4
        // phases 2..13
        for (int pp = 1; pp < 7; ++pp) {
            WAITVM(4);
            WRITES(b, 16384u);
            LOADS(a, (2 * pp + 2) * 128);
            WAITEX;
            ZREADS(16384u);
            WAITLG;
            ZSTORES((2 * pp - 1) * 128);
            __builtin_amdgcn_s_barrier();
            WAITVM(4);
            WRITES(a, 0u);
            LOADS(b, (2 * pp + 3) * 128);
            WAITEX;
            ZREADS(0u);
            WAITLG;
            ZSTORES((2 * pp) * 128);
            __builtin_amdgcn_s_barrier();
        }
        // phase 14
        WAITVM(4);
        WRITES(b, 16384u);
        WAITEX;
        ZREADS(16384u);
        WAITLG;
        ZSTORES(13 * 128);
        __builtin_amdgcn_s_barrier();                              // #17
        // phase 15
        WAITEX;
        ZREADS(0u);
        WAITLG;
        ZSTORES(14 * 128);
        __builtin_amdgcn_s_barrier();                              // #18
        // post
        WAITEX;
        ZREADS(16384u);
        WAITLG;
        ZSTORES(15 * 128);
    } else {
        // ===================== compute wave (R13: 2-ahead DS pipeline) =====================
        const int l   = lane & 31;            // lanes 32-63 duplicate 0-31
        const int gch = cbase + l;
        const float INV2PI = 0.15915494309189533577f;

        const float wo    = omegas[gch & (NU - 1)];
        const float sig   = 1.0f / (1.0f + __expf(-wo));
        const float a_rev = (sig * 19.5f + 0.5f) * 0.01f;
        const float Ca    = __builtin_amdgcn_cosf(a_rev);
        const float Sa    = __builtin_amdgcn_sinf(a_rev);

        float r        = r0[gch];
        const float p0 = phi0[gch];
        float s = __builtin_amdgcn_sinf(p0 * INV2PI);
        float c = __builtin_amdgcn_cosf(p0 * INV2PI);
        float acc = 0.0f;

        const unsigned vR = ldsb + (unsigned)l * 4u;
        const unsigned vI = vR + 32768u;
        const unsigned vZ = vR + 65536u;

        auto step = [&](float xr, float xi, float& zout) {
            const float kxi = xi * -0.05f;
            const float kxr = xr * 0.05f;
            const float eps = kxi * s;
            const float t1  = s * Ca;
            const float sA  = fmaf(c, Sa, t1);
            const float t2  = c * Ca;
            const float cA  = fmaf(-s, Sa, t2);
            const float rr  = r * r;
            const float g1  = fmaf(-rr, r, r);
            const float tr  = fmaf(kxr, c, r);
            r = fmaf(0.01f, g1, tr);
            s = fmaf(eps, cA, sA);
            c = fmaf(-eps, sA, cA);
            acc += eps;
            zout = r * c;
        };

        // 4 rotating input sets (static names; no runtime indexing)
        f2 S0r01, S0r23, S0i01, S0i23;
        f2 S1r01, S1r23, S1i01, S1i23;
        f2 S2r01, S2r23, S2i01, S2i23;
        f2 S3r01, S3r23, S3i01, S3i23;

#define RDs(it, S) { \
        const unsigned so_ = ((unsigned)((it) & 63)) * 512u; \
        const unsigned aR_ = vR + so_, aI_ = vI + so_; \
        asm volatile("ds_read2_b32 %0, %1 offset0:0 offset1:32"  : "=v"(S##r01) : "v"(aR_)); \
        asm volatile("ds_read2_b32 %0, %1 offset0:64 offset1:96" : "=v"(S##r23) : "v"(aR_)); \
        asm volatile("ds_read2_b32 %0, %1 offset0:0 offset1:32"  : "=v"(S##i01) : "v"(aI_)); \
        asm volatile("ds_read2_b32 %0, %1 offset0:64 offset1:96" : "=v"(S##i23) : "v"(aI_)); }

#define COMPs(it, S) { \
        float z0_, z1_, z2_, z3_; \
        step(S##r01.x, S##i01.x, z0_); step(S##r01.y, S##i01.y, z1_); \
        step(S##r23.x, S##i23.x, z2_); step(S##r23.y, S##i23.y, z3_); \
        const float m_ = fmaf(s, s, c * c); \
        const float n_ = fmaf(-0.5f, m_, 1.5f); \
        s *= n_; c *= n_; \
        const unsigned aZ_ = vZ + ((unsigned)((it) & 63)) * 512u; \
        asm volatile("ds_write2_b32 %0, %1, %2 offset0:0 offset1:32"  :: "v"(aZ_), "v"(z0_), "v"(z1_)); \
        asm volatile("ds_write2_b32 %0, %1, %2 offset0:64 offset1:96" :: "v"(aZ_), "v"(z2_), "v"(z3_)); }

#define WL(N) { asm volatile("s_waitcnt lgkmcnt(%0)" :: "n"(N) : "memory"); \
                __builtin_amdgcn_sched_barrier(0); }

        __builtin_amdgcn_s_barrier();                              // #1
        __builtin_amdgcn_s_barrier();                              // #2  (half0 sealed)

        for (int p = 0; p < 16; ++p) {
            const int s0 = p * 32;
            // prologue: 2 slots ahead (both within this sealed half)
            RDs(s0 + 0, S0); RDs(s0 + 1, S1);
            // k=0,1 (ramp waits: exact ops-after-target counts)
            RDs(s0 + 2, S2); WL(8);  COMPs(s0 + 0, S0);
            RDs(s0 + 3, S3); WL(10); COMPs(s0 + 1, S1);
            // k=2..29: steady, wait targets reads issued 2 iters ago
            for (int g = 0; g < 7; ++g) {
                const int k = s0 + 2 + g * 4;
                RDs(k + 2, S0); WL(12); COMPs(k + 0, S2);
                RDs(k + 3, S1); WL(12); COMPs(k + 1, S3);
                RDs(k + 4, S2); WL(12); COMPs(k + 2, S0);
                RDs(k + 5, S3); WL(12); COMPs(k + 3, S1);
            }
            // k=30,31: no more reads (look-ahead clamped at half boundary)
            WL(8); COMPs(s0 + 30, S2);
            WL(4); COMPs(s0 + 31, S3);
            asm volatile("s_waitcnt lgkmcnt(0)" ::: "memory");     // z writes sealed
            __builtin_amdgcn_s_barrier();                          // #3..#18
        }

        if (lane < 32) {
            r_f[gch] = r;
            phi_f[gch] = (float)((double)p0
                         + (double)a_rev * 2048.0 * 6.283185307179586476925287
                         + (double)acc);
        }
    }
}

extern "C" void kernel_launch(void* const* d_in, const int* in_sizes, int n_in,
                              void* d_out, int out_size, void* d_ws, size_t ws_size,
                              hipStream_t stream) {
    const float* Xr   = (const float*)d_in[0];
    const float* Xi   = (const float*)d_in[1];
    const float* r0   = (const float*)d_in[2];
    const float* phi0 = (const float*)d_in[3];
    const float* om   = (const float*)d_in[4];

    float* out   = (float*)d_out;
    float* zrp   = out;                               // Re(z): T*NCH floats
    float* r_f   = out + (size_t)2048 * NCH;          // NCH floats
    float* phi_f = r_f + NCH;                         // NCH floats

    reshopf_kernel<<<NBLK, 320, 0, stream>>>(Xr, Xi, r0, phi0, om, zrp, r_f, phi_f);
}